// Round 22
// baseline (128.317 us; speedup 1.0000x reference)
//
#include <hip/hip_runtime.h>
#include <math.h>

#define SEQ   2048
#define NH    16
#define HD    64
#define DM    1024
#define BATCH 2
#define MROWS (BATCH*SEQ)   // 4096
#define QSCALE (0.125f * 1.4426950408889634f)   // 1/sqrt(64) * log2(e): flash uses exp2

typedef __attribute__((ext_vector_type(8))) short short8;    // bf16x8 MFMA frag
typedef __attribute__((ext_vector_type(4))) float f32x4;     // fp32x4 acc (16x16)
typedef __attribute__((ext_vector_type(16))) float f32x16;   // fp32x16 acc (32x32)
typedef unsigned short ushort;
typedef unsigned int uint;

__device__ __forceinline__ ushort f2bf(float x){
  unsigned int u = __float_as_uint(x);
  unsigned int r = (u + 0x7fffu + ((u>>16)&1u)) >> 16;   // RNE
  return (ushort)r;
}
__device__ __forceinline__ float bf2f(ushort h){
  return __uint_as_float(((unsigned int)h) << 16);
}
__device__ __forceinline__ void gload16(const ushort* g, ushort* l){
  __builtin_amdgcn_global_load_lds(
      (const __attribute__((address_space(1))) unsigned int*)(g),
      (__attribute__((address_space(3))) unsigned int*)(l), 16, 0, 0);
}

// ---------------- cast fp32 -> bf16 (x + weights) + fused RoPE tables ----------------
__global__ void cast_all_kernel(
    const float* __restrict__ X,
    const float* __restrict__ wq, const float* __restrict__ wk,
    const float* __restrict__ wv, const float* __restrict__ wo,
    ushort* __restrict__ Xh,
    ushort* __restrict__ hq, ushort* __restrict__ hk,
    ushort* __restrict__ hv, ushort* __restrict__ ho,
    float* __restrict__ cosT, float* __restrict__ sinT)
{
  int idx = blockIdx.x*blockDim.x + threadIdx.x;
  if (idx < SEQ*32){                       // fused RoPE tables
    int i = idx & 31, l = idx >> 5;
    float e = (float)(2*i) / 64.0f;
    float inv = 1.0f / powf(10000.0f, e);
    float ang = (float)l * inv;
    cosT[idx] = cosf(ang);
    sinT[idx] = sinf(ang);
  }
  const float* src; ushort* dh; int off;
  const int NX = (MROWS*DM) >> 2;
  if (idx < NX){ src = X; dh = Xh; off = idx; }
  else {
    int t = idx - NX;
    int sel = t >> 18;
    off = t & 262143;
    src = sel==0 ? wq : sel==1 ? wk : sel==2 ? wv : wo;
    dh  = sel==0 ? hq : sel==1 ? hk : sel==2 ? hv : ho;
  }
  float4 v = ((const float4*)src)[off];
  uint2 hp;
  hp.x = (unsigned)f2bf(v.x) | ((unsigned)f2bf(v.y)<<16);
  hp.y = (unsigned)f2bf(v.z) | ((unsigned)f2bf(v.w)<<16);
  ((uint2*)dh)[off] = hp;
}

// ---------------- QKV projection: all outputs row-major coalesced (R19-verified) ----------------
__global__ __launch_bounds__(256) void gemm_qkv_mfma(
    const ushort* __restrict__ Xh,
    const ushort* __restrict__ Whq, const ushort* __restrict__ Whk, const ushort* __restrict__ Whv,
    const float* __restrict__ bq, const float* __restrict__ bk, const float* __restrict__ bv,
    const float* __restrict__ cosT, const float* __restrict__ sinT,
    ushort* __restrict__ Qb, ushort* __restrict__ Krow, ushort* __restrict__ Vrow)
{
  __shared__ __align__(16) ushort As[128*64];
  __shared__ __align__(16) ushort Bs[128*64];
  const int tid = threadIdx.x, w = tid>>6, lane = tid&63;
  const int c = lane & 15, g = lane >> 4;
  const int wr = w >> 1, wc = w & 1;
  const int m0   = blockIdx.x * 128;
  const int ncat = blockIdx.y * 128;
  const int which = ncat >> 10;          // 0=q 1=k 2=v
  const int n0    = ncat & 1023;
  const ushort* Bhi = which==0 ? Whq : which==1 ? Whk : Whv;
  const float*  bias= which==0 ? bq  : which==1 ? bk  : bv;

  const int srow = lane >> 3;
  const int scol = ((lane & 7) ^ srow) << 3;

  f32x4 acc[4][4] = {};
  for (int k0 = 0; k0 < DM; k0 += 64){
    __syncthreads();
    #pragma unroll
    for (int i=0;i<4;i++){
      const int rb = w*32 + i*8;
      gload16(Xh  + (size_t)(m0 + rb + srow)*DM + k0 + scol, &As[rb*64]);
      gload16(Bhi + (size_t)(n0 + rb + srow)*DM + k0 + scol, &Bs[rb*64]);
    }
    __syncthreads();
    #pragma unroll
    for (int kc=0;kc<2;kc++){
      short8 a[4], b[4];
      #pragma unroll
      for (int m=0;m<4;m++){
        int row = wr*64 + m*16 + c;
        a[m] = *(const short8*)&As[row*64 + ((((kc<<2)+g) ^ (row&7))<<3)];
      }
      #pragma unroll
      for (int n=0;n<4;n++){
        int row = wc*64 + n*16 + c;
        b[n] = *(const short8*)&Bs[row*64 + ((((kc<<2)+g) ^ (row&7))<<3)];
      }
      #pragma unroll
      for (int m=0;m<4;m++)
        #pragma unroll
        for (int n=0;n<4;n++)
          acc[m][n] = __builtin_amdgcn_mfma_f32_16x16x32_bf16(a[m], b[n], acc[m][n], 0,0,0);
    }
  }

  const int hh = (n0 + wc*64) >> 6;
  ushort* Out = which==0 ? Qb : which==1 ? Krow : Vrow;
  #pragma unroll
  for (int m=0;m<4;m++){
    #pragma unroll
    for (int r=0;r<4;r++){
      int mrow = m0 + wr*64 + m*16 + 4*g + r;
      int bb = mrow >> 11, l = mrow & (SEQ-1);
      size_t obase = (((size_t)bb*NH + hh)*SEQ + l)*HD;
      #pragma unroll
      for (int n=0;n<2;n++){
        int d1 = n*16 + c, d2 = d1 + 32;
        float v1 = acc[m][n  ][r] + bias[hh*64 + d1];
        float v2 = acc[m][n+2][r] + bias[hh*64 + d2];
        if (which < 2){
          float co = cosT[l*32 + d1], si = sinT[l*32 + d1];
          float o1 = v1*co - v2*si;
          float o2 = v2*co + v1*si;
          if (which == 0){ o1 *= QSCALE; o2 *= QSCALE; }
          Out[obase + d1] = f2bf(o1);
          Out[obase + d2] = f2bf(o2);
        } else {
          Out[obase + d1] = f2bf(v1);
          Out[obase + d2] = f2bf(v2);
        }
      }
    }
  }
}

// ---------------- imagize: row-major K/V -> flash tile-images (R19-verified) ----------------
__global__ __launch_bounds__(256) void imagize_kernel(
    const ushort* __restrict__ Krow, const ushort* __restrict__ Vrow,
    ushort* __restrict__ Kimg, ushort* __restrict__ Vimg)
{
  __shared__ __align__(16) ushort Lk[4096];
  __shared__ __align__(16) ushort Lv[4096];
  const int tid  = threadIdx.x;
  const int tile = blockIdx.x & 31;
  const int bh   = blockIdx.x >> 5;
  const size_t rbase = ((size_t)bh*SEQ + tile*64)*HD;

  const int l  = tid >> 2;          // 0..63
  const int d0 = (tid & 3) * 16;    // 0,16,32,48
  const int l31 = l & 31;
  const int kbl = (l >> 5) & 1;

  short8 a0 = *(const short8*)(Krow + rbase + (size_t)l*HD + d0);
  short8 a1 = *(const short8*)(Krow + rbase + (size_t)l*HD + d0 + 8);
  short8 v0 = *(const short8*)(Vrow + rbase + (size_t)l*HD + d0);
  short8 v1 = *(const short8*)(Vrow + rbase + (size_t)l*HD + d0 + 8);

  {
    int ch = kbl*4 + (d0>>4);
    *(short8*)&Lk[ch*512 + l31*8]      = a0;
    *(short8*)&Lk[ch*512 + (l31+32)*8] = a1;
  }
  {
    const int chb  = kbl*2 + ((l>>4)&1);
    const int posl = 32*((l>>3)&1);
    const int l7   = l & 7;
    #pragma unroll
    for (int j=0;j<8;j++){
      int d = d0 + j;
      Lv[((d>>5)*4 + chb)*512 + ((d&31) + posl)*8 + l7] = (ushort)v0[j];
    }
    #pragma unroll
    for (int j=0;j<8;j++){
      int d = d0 + 8 + j;
      Lv[((d>>5)*4 + chb)*512 + ((d&31) + posl)*8 + l7] = (ushort)v1[j];
    }
  }
  __syncthreads();

  const size_t ibase = ((size_t)bh*(SEQ/64) + tile)*4096;
  *(short8*)(Kimg + ibase + tid*16)     = *(const short8*)&Lk[tid*16];
  *(short8*)(Kimg + ibase + tid*16 + 8) = *(const short8*)&Lk[tid*16 + 8];
  *(short8*)(Vimg + ibase + tid*16)     = *(const short8*)&Lv[tid*16];
  *(short8*)(Vimg + ibase + tid*16 + 8) = *(const short8*)&Lv[tid*16 + 8];
}

// ---------------- MFMA flash attention: 8-wave blocks, 4-way key split ----------------
// Grid 1024 x 512 threads -> 4 blocks/CU x 8 waves = 8 waves/SIMD (hardware max).
// Additive partials (plain exp2-sum): O = sum(O_q), s = sum(s_q).
__global__ __launch_bounds__(512) void flash_mfma_kernel(
    const ushort* __restrict__ Qb, const ushort* __restrict__ Kb,
    const ushort* __restrict__ Vb,
    ushort* __restrict__ O0, ushort* __restrict__ O1,
    ushort* __restrict__ O2, ushort* __restrict__ O3,
    float* __restrict__ Ssum)
{
  __shared__ __align__(16) ushort Ks[2][8][512];
  __shared__ __align__(16) ushort Vs[2][8][512];

  const int tid  = threadIdx.x;
  const int w    = tid >> 6;           // 0..7
  const int lane = tid & 63;
  const int c    = lane & 31;
  const int h    = lane >> 5;

  // XCD swizzle over 1024 blocks (1024%8==0, bijective); each XCD chunk = one (b,quarter)
  // x all heads x all q-blocks -> 4 MB of K/V per chunk (L2-resident).
  const int hw = blockIdx.x;
  const int lg = (hw & 7)*128 + (hw >> 3);
  const int bx = lg & 7, hd = (lg >> 3) & 15, b = (lg >> 7) & 1, quarter = lg >> 8;
  const int bh = b*NH + hd;
  const int q0 = bx*256 + w*32;
  const int t0base = quarter*(SEQ/4);

  const ushort* Kimg = Kb + (size_t)bh*SEQ*HD;
  const ushort* Vimg = Vb + (size_t)bh*SEQ*HD;

  const ushort* Qrow = Qb + ((size_t)bh*SEQ + q0 + c)*HD + 8*h;
  short8 qf[4];
  #pragma unroll
  for (int kc=0;kc<4;kc++) qf[kc] = *(const short8*)(Qrow + kc*16);

  f32x16 oacc[2] = {};
  float ssum = 0.f;

  #define STAGE(bf, t0) { \
    gload16(Kimg + ((t0)>>6)*4096 + w*512 + lane*8, &Ks[bf][w][0]); \
    gload16(Vimg + ((t0)>>6)*4096 + w*512 + lane*8, &Vs[bf][w][0]); }

  STAGE(0, t0base)
  __syncthreads();

  int buf = 0;
  for (int t = 0; t < SEQ/4; t += 64){
    const int t0 = t0base + t;
    if (t + 64 < SEQ/4){
      STAGE(buf ^ 1, t0 + 64)
    }

    #pragma unroll
    for (int kb=0; kb<2; kb++){
      f32x16 s = {};
      __builtin_amdgcn_s_setprio(1);
      #pragma unroll
      for (int kc=0;kc<4;kc++){
        short8 kf = *(const short8*)&Ks[buf][kb*4+kc][lane*8];
        s = __builtin_amdgcn_mfma_f32_32x32x16_bf16(kf, qf[kc], s, 0,0,0);
      }
      __builtin_amdgcn_s_setprio(0);

      // p = exp2(s): log2(e) pre-folded into Q scale -> bare v_exp_f32, no mul
      uint pk[8];
      #pragma unroll
      for (int i=0;i<8;i++){
        float p0 = __builtin_amdgcn_exp2f(s[2*i]);
        float p1 = __builtin_amdgcn_exp2f(s[2*i+1]);
        ssum += p0 + p1;
        asm("v_cvt_pk_bf16_f32 %0, %1, %2" : "=v"(pk[i]) : "v"(p0), "v"(p1));
      }
      asm volatile("v_permlane32_swap_b32 %0, %1" : "+v"(pk[0]), "+v"(pk[2]));
      asm volatile("v_permlane32_swap_b32 %0, %1" : "+v"(pk[1]), "+v"(pk[3]));
      asm volatile("v_permlane32_swap_b32 %0, %1" : "+v"(pk[4]), "+v"(pk[6]));
      asm volatile("v_permlane32_swap_b32 %0, %1" : "+v"(pk[5]), "+v"(pk[7]));
      short8 pa0, pa1;
      ((uint*)&pa0)[0]=pk[0]; ((uint*)&pa0)[1]=pk[1]; ((uint*)&pa0)[2]=pk[2]; ((uint*)&pa0)[3]=pk[3];
      ((uint*)&pa1)[0]=pk[4]; ((uint*)&pa1)[1]=pk[5]; ((uint*)&pa1)[2]=pk[6]; ((uint*)&pa1)[3]=pk[7];

      __builtin_amdgcn_s_setprio(1);
      #pragma unroll
      for (int db=0; db<2; db++){
        short8 v0 = *(const short8*)&Vs[buf][db*4 + kb*2 + 0][lane*8];
        short8 v1 = *(const short8*)&Vs[buf][db*4 + kb*2 + 1][lane*8];
        oacc[db] = __builtin_amdgcn_mfma_f32_32x32x16_bf16(pa0, v0, oacc[db], 0,0,0);
        oacc[db] = __builtin_amdgcn_mfma_f32_32x32x16_bf16(pa1, v1, oacc[db], 0,0,0);
      }
      __builtin_amdgcn_s_setprio(0);
    }

    __syncthreads();
    buf ^= 1;
  }
  #undef STAGE

  {
    float a = ssum, bsw = ssum;
    asm volatile("v_permlane32_swap_b32 %0, %1" : "+v"(a), "+v"(bsw));
    ssum = a + bsw;
  }

  ushort* Op = quarter==0 ? O0 : quarter==1 ? O1 : quarter==2 ? O2 : O3;
  #pragma unroll
  for (int db=0; db<2; db++){
    #pragma unroll
    for (int r=0;r<16;r++){
      int q = q0 + (r&3) + 8*(r>>2) + 4*h;
      Op[((size_t)b*SEQ + q)*DM + hd*HD + db*32 + c] = f2bf(oacc[db][r]);
    }
  }
  if (h == 0){
    float* Sp = Ssum + (size_t)quarter*BATCH*NH*SEQ + ((size_t)b*NH + hd)*SEQ;
    Sp[q0 + c] = ssum;
  }
}

// ---------------- combine: AOh = (O0+O1+O2+O3)/(s0+s1+s2+s3), bf16 ----------------
__global__ void combine_kernel(
    const ushort* __restrict__ O0, const ushort* __restrict__ O1,
    const ushort* __restrict__ O2, const ushort* __restrict__ O3,
    const float* __restrict__ Ssum, ushort* __restrict__ AOh)
{
  const size_t NS = (size_t)BATCH*NH*SEQ;
  int i = blockIdx.x*blockDim.x + threadIdx.x;
  size_t e = (size_t)i*8;
  int d = (int)(e & (DM-1));
  int q = (int)((e >> 10) & (SEQ-1));
  int b = (int)(e >> 21);
  int hh = d >> 6;
  size_t sidx = ((size_t)b*NH + hh)*SEQ + q;
  float inv = 1.0f / (Ssum[sidx] + Ssum[NS + sidx] + Ssum[2*NS + sidx] + Ssum[3*NS + sidx]);
  short8 a0 = *(const short8*)(O0 + e);
  short8 a1 = *(const short8*)(O1 + e);
  short8 a2 = *(const short8*)(O2 + e);
  short8 a3 = *(const short8*)(O3 + e);
  short8 o;
  #pragma unroll
  for (int j=0;j<8;j++)
    o[j] = (short)f2bf((bf2f((ushort)a0[j]) + bf2f((ushort)a1[j])
                      + bf2f((ushort)a2[j]) + bf2f((ushort)a3[j]))*inv);
  *(short8*)(AOh + e) = o;
}

// ---------------- output projection: single-product bf16 GEMM (R9-verified) ----------------
__global__ __launch_bounds__(256) void gemm_o_mfma(
    const ushort* __restrict__ AOh, const ushort* __restrict__ Who,
    const float* __restrict__ bo, float* __restrict__ Y)
{
  __shared__ __align__(16) ushort As[128*64];
  __shared__ __align__(16) ushort Bs[128*64];
  const int tid = threadIdx.x, w = tid>>6, lane = tid&63;
  const int c = lane & 15, g = lane >> 4;
  const int wr = w >> 1, wc = w & 1;
  const int m0 = blockIdx.x * 128;
  const int n0 = blockIdx.y * 128;

  const int srow = lane >> 3;
  const int scol = ((lane & 7) ^ srow) << 3;

  f32x4 acc[4][4] = {};
  for (int k0 = 0; k0 < DM; k0 += 64){
    __syncthreads();
    #pragma unroll
    for (int i=0;i<4;i++){
      const int rb = w*32 + i*8;
      gload16(AOh + (size_t)(m0 + rb + srow)*DM + k0 + scol, &As[rb*64]);
      gload16(Who + (size_t)(n0 + rb + srow)*DM + k0 + scol, &Bs[rb*64]);
    }
    __syncthreads();
    #pragma unroll
    for (int kc=0;kc<2;kc++){
      short8 a[4], b[4];
      #pragma unroll
      for (int m=0;m<4;m++){
        int row = wr*64 + m*16 + c;
        a[m] = *(const short8*)&As[row*64 + ((((kc<<2)+g) ^ (row&7))<<3)];
      }
      #pragma unroll
      for (int n=0;n<4;n++){
        int row = wc*64 + n*16 + c;
        b[n] = *(const short8*)&Bs[row*64 + ((((kc<<2)+g) ^ (row&7))<<3)];
      }
      #pragma unroll
      for (int m=0;m<4;m++)
        #pragma unroll
        for (int n=0;n<4;n++)
          acc[m][n] = __builtin_amdgcn_mfma_f32_16x16x32_bf16(a[m], b[n], acc[m][n], 0,0,0);
    }
  }

  #pragma unroll
  for (int m=0;m<4;m++){
    #pragma unroll
    for (int r=0;r<4;r++){
      int mrow = m0 + wr*64 + m*16 + 4*g + r;
      #pragma unroll
      for (int n=0;n<4;n++){
        int ncol = n0 + wc*64 + n*16 + c;
        Y[(size_t)mrow*DM + ncol] = acc[m][n][r] + bo[ncol];
      }
    }
  }
}

extern "C" void kernel_launch(void* const* d_in, const int* in_sizes, int n_in,
                              void* d_out, int out_size, void* d_ws, size_t ws_size,
                              hipStream_t stream)
{
  const float* x  = (const float*)d_in[0];
  const float* qw = (const float*)d_in[1];
  const float* qb = (const float*)d_in[2];
  const float* kw = (const float*)d_in[3];
  const float* kb = (const float*)d_in[4];
  const float* vw = (const float*)d_in[5];
  const float* vb = (const float*)d_in[6];
  const float* ow = (const float*)d_in[7];
  const float* ob = (const float*)d_in[8];
  float* out = (float*)d_out;

  const size_t NE = (size_t)MROWS*DM;     // 4M
  const size_t WE = (size_t)DM*DM;        // 1M
  float* cosT = (float*)d_ws;
  float* sinT = cosT + SEQ*32;
  float* Ssum = sinT + SEQ*32;            // [4][B][NH][SEQ] fp32
  ushort* p = (ushort*)(Ssum + 4*BATCH*NH*SEQ);
  ushort* Xh   = p;           p += NE;    // dead after qkv -> Opart quarter 2
  ushort* Whq  = p;           p += WE;
  ushort* Whk  = p;           p += WE;
  ushort* Whv  = p;           p += WE;
  ushort* Who  = p;           p += WE;    // live until gemm_o
  ushort* Qb   = p;           p += NE;    // live through flash
  ushort* Krow = p;           p += NE;    // dead after imagize -> Opart quarter 0
  ushort* Vrow = p;           p += NE;    // dead after imagize -> Opart quarter 1
  ushort* Kimg = p;           p += NE;    // live through flash (NOT aliasable)
  ushort* Vimg = p;           p += NE;    // live through flash (NOT aliasable)
  ushort* AOh  = p;           p += NE;
  ushort* Oq3  = p;           p += NE;    // Opart quarter 3 (fresh)

  hipLaunchKernelGGL(cast_all_kernel, dim3((NE/4 + WE)/256), dim3(256), 0, stream,
                     x, qw, kw, vw, ow, Xh, Whq, Whk, Whv, Who, cosT, sinT);
  hipLaunchKernelGGL(gemm_qkv_mfma, dim3(MROWS/128, 3072/128), dim3(256), 0, stream,
                     Xh, Whq, Whk, Whv, qb, kb, vb, cosT, sinT, Qb, Krow, Vrow);
  hipLaunchKernelGGL(imagize_kernel, dim3(BATCH*NH*(SEQ/64)), dim3(256), 0, stream,
                     Krow, Vrow, Kimg, Vimg);
  hipLaunchKernelGGL(flash_mfma_kernel, dim3(1024), dim3(512), 0, stream,
                     Qb, Kimg, Vimg, Krow, Vrow, Xh, Oq3, Ssum);
  hipLaunchKernelGGL(combine_kernel, dim3(MROWS*DM/8/256), dim3(256), 0, stream,
                     Krow, Vrow, Xh, Oq3, Ssum, AOh);
  hipLaunchKernelGGL(gemm_o_mfma, dim3(MROWS/128, DM/128), dim3(256), 0, stream,
                     AOh, Who, ob, out);
}

// Round 23
// 122.627 us; speedup vs baseline: 1.0464x; 1.0464x over previous
//
#include <hip/hip_runtime.h>
#include <math.h>

#define SEQ   2048
#define NH    16
#define HD    64
#define DM    1024
#define BATCH 2
#define MROWS (BATCH*SEQ)   // 4096
#define QSCALE (0.125f * 1.4426950408889634f)   // 1/sqrt(64) * log2(e): flash uses exp2

typedef __attribute__((ext_vector_type(8))) short short8;    // bf16x8 MFMA frag
typedef __attribute__((ext_vector_type(4))) float f32x4;     // fp32x4 acc (16x16)
typedef __attribute__((ext_vector_type(16))) float f32x16;   // fp32x16 acc (32x32)
typedef unsigned short ushort;
typedef unsigned int uint;

__device__ __forceinline__ ushort f2bf(float x){
  unsigned int u = __float_as_uint(x);
  unsigned int r = (u + 0x7fffu + ((u>>16)&1u)) >> 16;   // RNE
  return (ushort)r;
}
__device__ __forceinline__ float bf2f(ushort h){
  return __uint_as_float(((unsigned int)h) << 16);
}
__device__ __forceinline__ void gload16(const ushort* g, ushort* l){
  __builtin_amdgcn_global_load_lds(
      (const __attribute__((address_space(1))) unsigned int*)(g),
      (__attribute__((address_space(3))) unsigned int*)(l), 16, 0, 0);
}

// ---------------- cast fp32 -> bf16 (x + weights) + fused RoPE tables ----------------
__global__ void cast_all_kernel(
    const float* __restrict__ X,
    const float* __restrict__ wq, const float* __restrict__ wk,
    const float* __restrict__ wv, const float* __restrict__ wo,
    ushort* __restrict__ Xh,
    ushort* __restrict__ hq, ushort* __restrict__ hk,
    ushort* __restrict__ hv, ushort* __restrict__ ho,
    float* __restrict__ cosT, float* __restrict__ sinT)
{
  int idx = blockIdx.x*blockDim.x + threadIdx.x;
  if (idx < SEQ*32){                       // fused RoPE tables
    int i = idx & 31, l = idx >> 5;
    float e = (float)(2*i) / 64.0f;
    float inv = 1.0f / powf(10000.0f, e);
    float ang = (float)l * inv;
    cosT[idx] = cosf(ang);
    sinT[idx] = sinf(ang);
  }
  const float* src; ushort* dh; int off;
  const int NX = (MROWS*DM) >> 2;
  if (idx < NX){ src = X; dh = Xh; off = idx; }
  else {
    int t = idx - NX;
    int sel = t >> 18;
    off = t & 262143;
    src = sel==0 ? wq : sel==1 ? wk : sel==2 ? wv : wo;
    dh  = sel==0 ? hq : sel==1 ? hk : sel==2 ? hv : ho;
  }
  float4 v = ((const float4*)src)[off];
  uint2 hp;
  hp.x = (unsigned)f2bf(v.x) | ((unsigned)f2bf(v.y)<<16);
  hp.y = (unsigned)f2bf(v.z) | ((unsigned)f2bf(v.w)<<16);
  ((uint2*)dh)[off] = hp;
}

// ---------------- QKV projection: all outputs row-major coalesced (R19-verified) ----------------
__global__ __launch_bounds__(256) void gemm_qkv_mfma(
    const ushort* __restrict__ Xh,
    const ushort* __restrict__ Whq, const ushort* __restrict__ Whk, const ushort* __restrict__ Whv,
    const float* __restrict__ bq, const float* __restrict__ bk, const float* __restrict__ bv,
    const float* __restrict__ cosT, const float* __restrict__ sinT,
    ushort* __restrict__ Qb, ushort* __restrict__ Krow, ushort* __restrict__ Vrow)
{
  __shared__ __align__(16) ushort As[128*64];
  __shared__ __align__(16) ushort Bs[128*64];
  const int tid = threadIdx.x, w = tid>>6, lane = tid&63;
  const int c = lane & 15, g = lane >> 4;
  const int wr = w >> 1, wc = w & 1;
  const int m0   = blockIdx.x * 128;
  const int ncat = blockIdx.y * 128;
  const int which = ncat >> 10;          // 0=q 1=k 2=v
  const int n0    = ncat & 1023;
  const ushort* Bhi = which==0 ? Whq : which==1 ? Whk : Whv;
  const float*  bias= which==0 ? bq  : which==1 ? bk  : bv;

  const int srow = lane >> 3;
  const int scol = ((lane & 7) ^ srow) << 3;

  f32x4 acc[4][4] = {};
  for (int k0 = 0; k0 < DM; k0 += 64){
    __syncthreads();
    #pragma unroll
    for (int i=0;i<4;i++){
      const int rb = w*32 + i*8;
      gload16(Xh  + (size_t)(m0 + rb + srow)*DM + k0 + scol, &As[rb*64]);
      gload16(Bhi + (size_t)(n0 + rb + srow)*DM + k0 + scol, &Bs[rb*64]);
    }
    __syncthreads();
    #pragma unroll
    for (int kc=0;kc<2;kc++){
      short8 a[4], b[4];
      #pragma unroll
      for (int m=0;m<4;m++){
        int row = wr*64 + m*16 + c;
        a[m] = *(const short8*)&As[row*64 + ((((kc<<2)+g) ^ (row&7))<<3)];
      }
      #pragma unroll
      for (int n=0;n<4;n++){
        int row = wc*64 + n*16 + c;
        b[n] = *(const short8*)&Bs[row*64 + ((((kc<<2)+g) ^ (row&7))<<3)];
      }
      #pragma unroll
      for (int m=0;m<4;m++)
        #pragma unroll
        for (int n=0;n<4;n++)
          acc[m][n] = __builtin_amdgcn_mfma_f32_16x16x32_bf16(a[m], b[n], acc[m][n], 0,0,0);
    }
  }

  const int hh = (n0 + wc*64) >> 6;
  ushort* Out = which==0 ? Qb : which==1 ? Krow : Vrow;
  #pragma unroll
  for (int m=0;m<4;m++){
    #pragma unroll
    for (int r=0;r<4;r++){
      int mrow = m0 + wr*64 + m*16 + 4*g + r;
      int bb = mrow >> 11, l = mrow & (SEQ-1);
      size_t obase = (((size_t)bb*NH + hh)*SEQ + l)*HD;
      #pragma unroll
      for (int n=0;n<2;n++){
        int d1 = n*16 + c, d2 = d1 + 32;
        float v1 = acc[m][n  ][r] + bias[hh*64 + d1];
        float v2 = acc[m][n+2][r] + bias[hh*64 + d2];
        if (which < 2){
          float co = cosT[l*32 + d1], si = sinT[l*32 + d1];
          float o1 = v1*co - v2*si;
          float o2 = v2*co + v1*si;
          if (which == 0){ o1 *= QSCALE; o2 *= QSCALE; }
          Out[obase + d1] = f2bf(o1);
          Out[obase + d2] = f2bf(o2);
        } else {
          Out[obase + d1] = f2bf(v1);
          Out[obase + d2] = f2bf(v2);
        }
      }
    }
  }
}

// ---------------- imagize: row-major K/V -> flash tile-images (R19-verified) ----------------
__global__ __launch_bounds__(256) void imagize_kernel(
    const ushort* __restrict__ Krow, const ushort* __restrict__ Vrow,
    ushort* __restrict__ Kimg, ushort* __restrict__ Vimg)
{
  __shared__ __align__(16) ushort Lk[4096];
  __shared__ __align__(16) ushort Lv[4096];
  const int tid  = threadIdx.x;
  const int tile = blockIdx.x & 31;
  const int bh   = blockIdx.x >> 5;
  const size_t rbase = ((size_t)bh*SEQ + tile*64)*HD;

  const int l  = tid >> 2;          // 0..63
  const int d0 = (tid & 3) * 16;    // 0,16,32,48
  const int l31 = l & 31;
  const int kbl = (l >> 5) & 1;

  short8 a0 = *(const short8*)(Krow + rbase + (size_t)l*HD + d0);
  short8 a1 = *(const short8*)(Krow + rbase + (size_t)l*HD + d0 + 8);
  short8 v0 = *(const short8*)(Vrow + rbase + (size_t)l*HD + d0);
  short8 v1 = *(const short8*)(Vrow + rbase + (size_t)l*HD + d0 + 8);

  {
    int ch = kbl*4 + (d0>>4);
    *(short8*)&Lk[ch*512 + l31*8]      = a0;
    *(short8*)&Lk[ch*512 + (l31+32)*8] = a1;
  }
  {
    const int chb  = kbl*2 + ((l>>4)&1);
    const int posl = 32*((l>>3)&1);
    const int l7   = l & 7;
    #pragma unroll
    for (int j=0;j<8;j++){
      int d = d0 + j;
      Lv[((d>>5)*4 + chb)*512 + ((d&31) + posl)*8 + l7] = (ushort)v0[j];
    }
    #pragma unroll
    for (int j=0;j<8;j++){
      int d = d0 + 8 + j;
      Lv[((d>>5)*4 + chb)*512 + ((d&31) + posl)*8 + l7] = (ushort)v1[j];
    }
  }
  __syncthreads();

  const size_t ibase = ((size_t)bh*(SEQ/64) + tile)*4096;
  *(short8*)(Kimg + ibase + tid*16)     = *(const short8*)&Lk[tid*16];
  *(short8*)(Kimg + ibase + tid*16 + 8) = *(const short8*)&Lk[tid*16 + 8];
  *(short8*)(Vimg + ibase + tid*16)     = *(const short8*)&Lv[tid*16];
  *(short8*)(Vimg + ibase + tid*16 + 8) = *(const short8*)&Lv[tid*16 + 8];
}

// ---------------- MFMA flash attention (R21-verified): 8-wave, 2-way key-split, exp2 ----------------
__global__ __launch_bounds__(512) void flash_mfma_kernel(
    const ushort* __restrict__ Qb, const ushort* __restrict__ Kb,
    const ushort* __restrict__ Vb, ushort* __restrict__ Opart, float* __restrict__ Ssum)
{
  __shared__ __align__(16) ushort Ks[2][8][512];
  __shared__ __align__(16) ushort Vs[2][8][512];

  const int tid  = threadIdx.x;
  const int w    = tid >> 6;           // 0..7
  const int lane = tid & 63;
  const int c    = lane & 31;
  const int h    = lane >> 5;

  const int hw = blockIdx.x;
  const int lg = (hw & 7)*64 + (hw >> 3);
  const int bx = lg & 7, hd = (lg >> 3) & 15, b = (lg >> 7) & 1, half = lg >> 8;
  const int bh = b*NH + hd;
  const int q0 = bx*256 + w*32;
  const int t0base = half*(SEQ/2);

  const ushort* Kimg = Kb + (size_t)bh*SEQ*HD;
  const ushort* Vimg = Vb + (size_t)bh*SEQ*HD;

  const ushort* Qrow = Qb + ((size_t)bh*SEQ + q0 + c)*HD + 8*h;
  short8 qf[4];
  #pragma unroll
  for (int kc=0;kc<4;kc++) qf[kc] = *(const short8*)(Qrow + kc*16);

  f32x16 oacc[2] = {};
  float ssum = 0.f;

  #define STAGE(bf, t0) { \
    gload16(Kimg + ((t0)>>6)*4096 + w*512 + lane*8, &Ks[bf][w][0]); \
    gload16(Vimg + ((t0)>>6)*4096 + w*512 + lane*8, &Vs[bf][w][0]); }

  STAGE(0, t0base)
  __syncthreads();

  int buf = 0;
  for (int t = 0; t < SEQ/2; t += 64){
    const int t0 = t0base + t;
    if (t + 64 < SEQ/2){
      STAGE(buf ^ 1, t0 + 64)
    }

    #pragma unroll
    for (int kb=0; kb<2; kb++){
      f32x16 s = {};
      __builtin_amdgcn_s_setprio(1);
      #pragma unroll
      for (int kc=0;kc<4;kc++){
        short8 kf = *(const short8*)&Ks[buf][kb*4+kc][lane*8];
        s = __builtin_amdgcn_mfma_f32_32x32x16_bf16(kf, qf[kc], s, 0,0,0);
      }
      __builtin_amdgcn_s_setprio(0);

      // p = exp2(s): log2(e) pre-folded into Q scale -> bare v_exp_f32, no mul
      uint pk[8];
      #pragma unroll
      for (int i=0;i<8;i++){
        float p0 = __builtin_amdgcn_exp2f(s[2*i]);
        float p1 = __builtin_amdgcn_exp2f(s[2*i+1]);
        ssum += p0 + p1;
        asm("v_cvt_pk_bf16_f32 %0, %1, %2" : "=v"(pk[i]) : "v"(p0), "v"(p1));
      }
      asm volatile("v_permlane32_swap_b32 %0, %1" : "+v"(pk[0]), "+v"(pk[2]));
      asm volatile("v_permlane32_swap_b32 %0, %1" : "+v"(pk[1]), "+v"(pk[3]));
      asm volatile("v_permlane32_swap_b32 %0, %1" : "+v"(pk[4]), "+v"(pk[6]));
      asm volatile("v_permlane32_swap_b32 %0, %1" : "+v"(pk[5]), "+v"(pk[7]));
      short8 pa0, pa1;
      ((uint*)&pa0)[0]=pk[0]; ((uint*)&pa0)[1]=pk[1]; ((uint*)&pa0)[2]=pk[2]; ((uint*)&pa0)[3]=pk[3];
      ((uint*)&pa1)[0]=pk[4]; ((uint*)&pa1)[1]=pk[5]; ((uint*)&pa1)[2]=pk[6]; ((uint*)&pa1)[3]=pk[7];

      __builtin_amdgcn_s_setprio(1);
      #pragma unroll
      for (int db=0; db<2; db++){
        short8 v0 = *(const short8*)&Vs[buf][db*4 + kb*2 + 0][lane*8];
        short8 v1 = *(const short8*)&Vs[buf][db*4 + kb*2 + 1][lane*8];
        oacc[db] = __builtin_amdgcn_mfma_f32_32x32x16_bf16(pa0, v0, oacc[db], 0,0,0);
        oacc[db] = __builtin_amdgcn_mfma_f32_32x32x16_bf16(pa1, v1, oacc[db], 0,0,0);
      }
      __builtin_amdgcn_s_setprio(0);
    }

    __syncthreads();
    buf ^= 1;
  }
  #undef STAGE

  {
    float a = ssum, bsw = ssum;
    asm volatile("v_permlane32_swap_b32 %0, %1" : "+v"(a), "+v"(bsw));
    ssum = a + bsw;
  }

  ushort* Op = Opart + (size_t)half*MROWS*DM;
  #pragma unroll
  for (int db=0; db<2; db++){
    #pragma unroll
    for (int r=0;r<16;r++){
      int q = q0 + (r&3) + 8*(r>>2) + 4*h;
      Op[((size_t)b*SEQ + q)*DM + hd*HD + db*32 + c] = f2bf(oacc[db][r]);
    }
  }
  if (h == 0){
    float* Sp = Ssum + (size_t)half*BATCH*NH*SEQ + ((size_t)b*NH + hd)*SEQ;
    Sp[q0 + c] = ssum;
  }
}

// ---------------- combine: AOh = (O0+O1)/(s0+s1), bf16 ----------------
__global__ void combine_kernel(const ushort* __restrict__ Opart, const float* __restrict__ Ssum,
                               ushort* __restrict__ AOh)
{
  const size_t NE = (size_t)MROWS*DM;
  int i = blockIdx.x*blockDim.x + threadIdx.x;
  size_t e = (size_t)i*8;
  int d = (int)(e & (DM-1));
  int q = (int)((e >> 10) & (SEQ-1));
  int b = (int)(e >> 21);
  int hh = d >> 6;
  size_t sidx = ((size_t)b*NH + hh)*SEQ + q;
  float inv = 1.0f / (Ssum[sidx] + Ssum[(size_t)BATCH*NH*SEQ + sidx]);
  short8 a = *(const short8*)(Opart + e);
  short8 bb = *(const short8*)(Opart + NE + e);
  short8 o;
  #pragma unroll
  for (int j=0;j<8;j++)
    o[j] = (short)f2bf((bf2f((ushort)a[j]) + bf2f((ushort)bb[j]))*inv);
  *(short8*)(AOh + e) = o;
}

// ---------------- output projection: single-product bf16 GEMM (R9-verified) ----------------
__global__ __launch_bounds__(256) void gemm_o_mfma(
    const ushort* __restrict__ AOh, const ushort* __restrict__ Who,
    const float* __restrict__ bo, float* __restrict__ Y)
{
  __shared__ __align__(16) ushort As[128*64];
  __shared__ __align__(16) ushort Bs[128*64];
  const int tid = threadIdx.x, w = tid>>6, lane = tid&63;
  const int c = lane & 15, g = lane >> 4;
  const int wr = w >> 1, wc = w & 1;
  const int m0 = blockIdx.x * 128;
  const int n0 = blockIdx.y * 128;

  const int srow = lane >> 3;
  const int scol = ((lane & 7) ^ srow) << 3;

  f32x4 acc[4][4] = {};
  for (int k0 = 0; k0 < DM; k0 += 64){
    __syncthreads();
    #pragma unroll
    for (int i=0;i<4;i++){
      const int rb = w*32 + i*8;
      gload16(AOh + (size_t)(m0 + rb + srow)*DM + k0 + scol, &As[rb*64]);
      gload16(Who + (size_t)(n0 + rb + srow)*DM + k0 + scol, &Bs[rb*64]);
    }
    __syncthreads();
    #pragma unroll
    for (int kc=0;kc<2;kc++){
      short8 a[4], b[4];
      #pragma unroll
      for (int m=0;m<4;m++){
        int row = wr*64 + m*16 + c;
        a[m] = *(const short8*)&As[row*64 + ((((kc<<2)+g) ^ (row&7))<<3)];
      }
      #pragma unroll
      for (int n=0;n<4;n++){
        int row = wc*64 + n*16 + c;
        b[n] = *(const short8*)&Bs[row*64 + ((((kc<<2)+g) ^ (row&7))<<3)];
      }
      #pragma unroll
      for (int m=0;m<4;m++)
        #pragma unroll
        for (int n=0;n<4;n++)
          acc[m][n] = __builtin_amdgcn_mfma_f32_16x16x32_bf16(a[m], b[n], acc[m][n], 0,0,0);
    }
  }

  #pragma unroll
  for (int m=0;m<4;m++){
    #pragma unroll
    for (int r=0;r<4;r++){
      int mrow = m0 + wr*64 + m*16 + 4*g + r;
      #pragma unroll
      for (int n=0;n<4;n++){
        int ncol = n0 + wc*64 + n*16 + c;
        Y[(size_t)mrow*DM + ncol] = acc[m][n][r] + bo[ncol];
      }
    }
  }
}

extern "C" void kernel_launch(void* const* d_in, const int* in_sizes, int n_in,
                              void* d_out, int out_size, void* d_ws, size_t ws_size,
                              hipStream_t stream)
{
  const float* x  = (const float*)d_in[0];
  const float* qw = (const float*)d_in[1];
  const float* qb = (const float*)d_in[2];
  const float* kw = (const float*)d_in[3];
  const float* kb = (const float*)d_in[4];
  const float* vw = (const float*)d_in[5];
  const float* vb = (const float*)d_in[6];
  const float* ow = (const float*)d_in[7];
  const float* ob = (const float*)d_in[8];
  float* out = (float*)d_out;

  const size_t NE = (size_t)MROWS*DM;     // 4M
  const size_t WE = (size_t)DM*DM;        // 1M
  float* cosT = (float*)d_ws;
  float* sinT = cosT + SEQ*32;
  float* Ssum = sinT + SEQ*32;            // [2][B][NH][SEQ] fp32
  ushort* p = (ushort*)(Ssum + 2*BATCH*NH*SEQ);
  ushort* Xh   = p;           p += NE;
  ushort* Whq  = p;           p += WE;
  ushort* Whk  = p;           p += WE;
  ushort* Whv  = p;           p += WE;
  ushort* Who  = p;           p += WE;
  ushort* Qb   = p;           p += NE;
  ushort* Krow = p;           p += NE;    // row-major K (RoPE'd); later aliased by Opart[0]
  ushort* Vrow = p;           p += NE;    // row-major V;          later aliased by Opart[1]
  ushort* Kimg = p;           p += NE;    // K tile-image [bh][L/64][8][512]
  ushort* Vimg = p;           p += NE;    // V tile-image
  ushort* AOh  = p;           p += NE;
  ushort* Opart = Krow;                   // [2][B,S,D] partials alias Krow+Vrow (dead after imagize)

  hipLaunchKernelGGL(cast_all_kernel, dim3((NE/4 + WE)/256), dim3(256), 0, stream,
                     x, qw, kw, vw, ow, Xh, Whq, Whk, Whv, Who, cosT, sinT);
  hipLaunchKernelGGL(gemm_qkv_mfma, dim3(MROWS/128, 3072/128), dim3(256), 0, stream,
                     Xh, Whq, Whk, Whv, qb, kb, vb, cosT, sinT, Qb, Krow, Vrow);
  hipLaunchKernelGGL(imagize_kernel, dim3(BATCH*NH*(SEQ/64)), dim3(256), 0, stream,
                     Krow, Vrow, Kimg, Vimg);
  hipLaunchKernelGGL(flash_mfma_kernel, dim3(512), dim3(512), 0, stream,
                     Qb, Kimg, Vimg, Opart, Ssum);
  hipLaunchKernelGGL(combine_kernel, dim3(MROWS*DM/8/256), dim3(256), 0, stream,
                     Opart, Ssum, AOh);
  hipLaunchKernelGGL(gemm_o_mfma, dim3(MROWS/128, DM/128), dim3(256), 0, stream,
                     AOh, Who, ob, out);
}